// Round 4
// baseline (526.421 us; speedup 1.0000x reference)
//
#include <hip/hip_runtime.h>
#include <hip/hip_bf16.h>
#include <stdint.h>

// Mahalanobis loss via Gram reformulation:
//   mean_n (f_n-mu)^T C (f_n-mu)
//     = (1/N)[ <C, G> - sum_{d,e} C_de (coef_d mu_e + mu_d coef_e) ],
//   G = Fb^T Fb (bf16, fp32 accum), s = sum_n fb_n, coef = s - (N/2) mu.
//
// R7: R6's gram didn't improve despite zero-VALU staging. Diagnosis: Ft rows
// are 256KB apart, so a chunk's 512 16B-segments share identical addr bits
// [0:17] -> L2-channel hotspot serializes staging. Fix: Ft is now TILED +
// PRE-SWIZZLED: 16KB blocks B[p][m] (p = d-panel of 128, m = n-chunk of 64)
// that are the exact byte image of a gram LDS slot (XOR bank swizzle baked in
// by prep). gram staging per chunk = contiguous 16KB per panel (each gld16 a
// contiguous 1KB), channel-spread; LDS-read indexing unchanged. Prep bakes
// the swizzle by XORing the phase-1 LDS write column (phase-2 linear; bank
// pattern identical to the verified-free one). gram loop reordered: ds_reads
// -> lgkmcnt -> barrier2 -> issue(c+2) -> MFMA (loads get ~2.5 iters of
// flight, MFMA overlaps load issue); s_setprio around the MFMA cluster.

typedef __attribute__((ext_vector_type(8))) short short8;
typedef __attribute__((ext_vector_type(4))) float floatx4;

static constexpr int NROWS = 131072;
static constexpr int DDIM  = 512;

__device__ __forceinline__ short f2bf(float f) {
  __bf16 b = (__bf16)f;                   // RNE f32->bf16
  return __builtin_bit_cast(short, b);
}
__device__ __forceinline__ float bf2f(short s) {
  __bf16 b = __builtin_bit_cast(__bf16, s);
  return (float)b;
}

__device__ __forceinline__ void gld16(const void* g, void* l) {
  __builtin_amdgcn_global_load_lds(
      (const __attribute__((address_space(1))) void*)g,
      (__attribute__((address_space(3))) void*)l, 16, 0, 0);
}

// ---- zero-init: s[512] and out (both poisoned 0xAA before every launch) ----
__global__ __launch_bounds__(512) void maha_zero(float* __restrict__ s_ws,
                                                 float* __restrict__ out) {
  s_ws[threadIdx.x] = 0.0f;
  if (threadIdx.x == 0) out[0] = 0.0f;
}

// ---- pre-pass: F[n][d] f32 -> tiled/swizzled Ft blocks, fused s[d] ----
// Ft block B[p][m] = 8192 shorts: row r (0..127) at shorts [r*64, +64);
// short j of row r holds element n = 64m + (j ^ ((r&7)<<3)), d = 128p + r.
// Prep tile: 256 n x 64 d per block. Grid 512 x 8 = 4096 blocks.
__global__ __launch_bounds__(256) void maha_prep(const float* __restrict__ F,
                                                 short* __restrict__ Ft,
                                                 float* __restrict__ s_ws) {
  __shared__ short T[64][280];            // row stride 560B (16B-aligned)
  const int bn = blockIdx.x & 511;        // n-stripe (256 rows)
  const int bd = blockIdx.x >> 9;         // d-window (64 cols)
  const int n0 = bn * 256, d0 = bd * 64;
  const int t = threadIdx.x;

  // phase 1: thread t reads row n0+t cols [d0,d0+64); writes LDS with the
  // gram swizzle baked into the column: col = t ^ ((row&7)<<3).
  const float* rp = F + (size_t)(n0 + t) * DDIM + d0;
#pragma unroll
  for (int k = 0; k < 16; k++) {
    floatx4 v4 = *(const floatx4*)(rp + 4 * k);
#pragma unroll
    for (int j = 0; j < 4; j++) {
      const int row = 4 * k + j;
      T[row][t ^ ((row & 7) << 3)] = f2bf(v4[j]);
    }
  }
  __syncthreads();

  // phase 2: thread (d = t>>2, part = t&3) streams T[d][64*part..+64) out
  // linearly (data already in block-image order). Bank-quad = (3d+i)&7:
  // permutation over d mod 8 -> 2 lanes/bank (free).
  const int d = t >> 2, part = t & 3;
  const int dg = d0 + d;
  const int p = dg >> 7, r = dg & 127;
  const int m = (n0 >> 6) + part;
  float s = 0.f;
  short* orow = Ft + ((size_t)(p * 2048 + m) << 13) + r * 64;
#pragma unroll
  for (int i = 0; i < 8; i++) {
    short8 w = *(const short8*)&T[d][64 * part + 8 * i];
    *(short8*)(orow + 8 * i) = w;
#pragma unroll
    for (int j = 0; j < 8; j++) s += bf2f(w[j]);
  }
  s += __shfl_down(s, 1);                 // reduce 4 consecutive lanes
  s += __shfl_down(s, 2);
  if (part == 0) atomicAdd(&s_ws[dg], s); // 512 adds per address total
}

// ---- main: symmetric Gram tiles from tiled Ft, fused <C,G> epilogue ----
__global__ __launch_bounds__(512, 2) void maha_gram(const short* __restrict__ Ft,
                                                    const float* __restrict__ C,
                                                    float* __restrict__ out) {
  // A dbuf: ABs[0..16384) shorts, B dbuf: ABs[16384..32768). 64 KB total.
  // Slot = byte-for-byte image of one Ft block (swizzle already applied).
  __shared__ short ABs[32768];
  __shared__ float red[8];

  static const int TI[10] = {0,0,0,0,1,1,1,2,2,3};
  static const int TJ[10] = {0,1,2,3,1,2,3,2,3,3};

  const int bid  = blockIdx.x;
  const int gg   = bid / 80;
  const int rr   = bid % 80;
  const int slab = gg * 8 + (rr & 7);     // 0..127, 1024 K-rows each
  const int tile = rr >> 3;               // 0..9
  const int ti = TI[tile], tj = TJ[tile];
  const bool diag = (ti == tj);

  const int th = threadIdx.x;
  const int wave = th >> 6, lane = th & 63;

  // ---- staging: per chunk, A-panel block = contiguous 16 KB; wave w copies
  // bytes [w*1024,+1024) and [8192+w*1024,+1024) (2 gld16), B same.
  const char* FtB = (const char*)Ft;
  const int woff = wave * 1024;               // wave-uniform LDS offset
  const int goff = woff + lane * 16;          // per-lane global offset
  char* lABs = (char*)ABs;

  auto issue = [&](int c) {               // 4 loads/wave (2 if diag)
    const size_t m = (size_t)slab * 16 + c;
    const char* blkA = FtB + (((size_t)ti * 2048 + m) << 14);
    char* lbase = lABs + (c & 1) * 16384;
    gld16(blkA + goff, lbase + woff);
    gld16(blkA + 8192 + goff, lbase + 8192 + woff);
    if (!diag) {
      const char* blkB = FtB + (((size_t)tj * 2048 + m) << 14);
      gld16(blkB + goff, lbase + 32768 + woff);
      gld16(blkB + 8192 + goff, lbase + 32768 + 8192 + woff);
    }
  };

  // ---- MFMA mapping: 2x2 spatial x 2-way K-split over the 128x128 tile ----
  const int wk = wave & 1;                // K-half of the 64-row chunk
  const int wm = (wave >> 1) & 1;
  const int wn = wave >> 2;
  const int l15 = lane & 15, quad = lane >> 4;
  const int kb = wk * 64 + quad * 16;     // byte offset of this lane's K-slice

  int idxA[4], idxB[4];                   // constant short-offsets (per slot)
#pragma unroll
  for (int mi = 0; mi < 4; mi++) {
    const int r = wm * 64 + mi * 16 + l15;
    idxA[mi] = r * 64 + ((kb ^ ((r & 7) << 4)) >> 1);
    const int e = wn * 64 + mi * 16 + l15;
    idxB[mi] = e * 64 + ((kb ^ ((e & 7) << 4)) >> 1);
  }
  const int bbase = diag ? 0 : 16384;     // diag reads B from the A buffer

  floatx4 acc[4][4];
#pragma unroll
  for (int i = 0; i < 4; i++)
#pragma unroll
    for (int j = 0; j < 4; j++) acc[i][j] = floatx4{0.f, 0.f, 0.f, 0.f};

  issue(0);
  issue(1);

#pragma unroll 2
  for (int c = 0; c < 16; ++c) {
    // counted wait: leave chunk c+1's loads in flight (drain only at c=15)
    if (c == 15)      asm volatile("s_waitcnt vmcnt(0)" ::: "memory");
    else if (diag)    asm volatile("s_waitcnt vmcnt(2)" ::: "memory");
    else              asm volatile("s_waitcnt vmcnt(4)" ::: "memory");
    __builtin_amdgcn_s_barrier();         // slot c fully staged for all waves
    const int sb = (c & 1) * 8192;
    short8 af[4], bf[4];
#pragma unroll
    for (int mi = 0; mi < 4; mi++) af[mi] = *(const short8*)&ABs[sb + idxA[mi]];
#pragma unroll
    for (int fj = 0; fj < 4; fj++) bf[fj] = *(const short8*)&ABs[bbase + sb + idxB[fj]];
    asm volatile("s_waitcnt lgkmcnt(0)" ::: "memory");  // my slot-c reads retired
    __builtin_amdgcn_s_barrier();         // all waves done reading slot c
    if (c < 14) issue(c + 2);             // overwrite slot c; overlaps MFMA below
    __builtin_amdgcn_s_setprio(1);
#pragma unroll
    for (int fj = 0; fj < 4; fj++)
#pragma unroll
      for (int mi = 0; mi < 4; mi++)
        acc[mi][fj] = __builtin_amdgcn_mfma_f32_16x16x32_bf16(
            af[mi], bf[fj], acc[mi][fj], 0, 0, 0);
    __builtin_amdgcn_s_setprio(0);
  }

  // ---- epilogue: psum = sum W_de * G_de, W = C_ij (+ C_ji^T if offdiag) ----
  // K-split partners (wk=0/1) hold partial G for the same (d,e) region; both
  // contract with the same C weights -> psum adds correctly across waves.
  const int d0 = ti * 128, e0 = tj * 128;
  float psum = 0.f;
#pragma unroll
  for (int mi = 0; mi < 4; mi++) {
#pragma unroll
    for (int fj = 0; fj < 4; fj++) {
      const int dg = d0 + wm * 64 + mi * 16 + quad * 4;
      const int eg = e0 + wn * 64 + fj * 16 + l15;
#pragma unroll
      for (int r2 = 0; r2 < 4; r2++) {
        float wgt = C[(size_t)(dg + r2) * DDIM + eg];
        if (!diag) wgt += C[(size_t)eg * DDIM + dg + r2];
        psum += wgt * acc[mi][fj][r2];
      }
    }
  }

#pragma unroll
  for (int off = 32; off > 0; off >>= 1) psum += __shfl_down(psum, off);
  if (lane == 0) red[wave] = psum;
  __syncthreads();
  if (th == 0) {
    const float tot = red[0] + red[1] + red[2] + red[3] +
                      red[4] + red[5] + red[6] + red[7];
    atomicAdd(out, tot * (1.0f / (float)NROWS));
  }
}

// ---- correction: out += -(1/N) sum_{d,e} C_de (coef_d mu_e + mu_d coef_e) ----
__global__ __launch_bounds__(256) void maha_corr(const float* __restrict__ C,
                                                 const float* __restrict__ mu,
                                                 const float* __restrict__ s_ws,
                                                 float* __restrict__ out) {
  __shared__ float red[4];
  const int b = blockIdx.x;               // 128 blocks x 4 d-rows
  const int th = threadIdx.x;
  float cd[4], md[4];
#pragma unroll
  for (int dd = 0; dd < 4; dd++) {
    const int d = b * 4 + dd;
    md[dd] = mu[d];
    cd[dd] = s_ws[d] - 0.5f * (float)NROWS * md[dd];
  }
  float p = 0.f;
#pragma unroll
  for (int rep = 0; rep < 2; rep++) {
    const int e = th + rep * 256;
    const float me = mu[e];
    const float ce = s_ws[e] - 0.5f * (float)NROWS * me;
#pragma unroll
    for (int dd = 0; dd < 4; dd++)
      p += C[(size_t)(b * 4 + dd) * DDIM + e] * (cd[dd] * me + md[dd] * ce);
  }
  const int lane = th & 63, wave = th >> 6;
#pragma unroll
  for (int off = 32; off > 0; off >>= 1) p += __shfl_down(p, off);
  if (lane == 0) red[wave] = p;
  __syncthreads();
  if (th == 0)
    atomicAdd(out, -(red[0] + red[1] + red[2] + red[3]) * (1.0f / (float)NROWS));
}

extern "C" void kernel_launch(void* const* d_in, const int* in_sizes, int n_in,
                              void* d_out, int out_size, void* d_ws, size_t ws_size,
                              hipStream_t stream) {
  const float* feature = (const float*)d_in[0];   // [131072, 512] fp32
  const float* mean    = (const float*)d_in[1];   // [512] fp32
  const float* invcov  = (const float*)d_in[2];   // [512, 512] fp32
  float* out = (float*)d_out;                     // scalar fp32
  float* s_ws = (float*)d_ws;                     // s[512] fp32
  short* Ft   = (short*)((char*)d_ws + 4096);     // tiled blocks, 134 MB

  maha_zero<<<1, 512, 0, stream>>>(s_ws, out);
  maha_prep<<<4096, 256, 0, stream>>>(feature, Ft, s_ws);
  maha_gram<<<1280, 512, 0, stream>>>(Ft, invcov, out);
  maha_corr<<<128, 256, 0, stream>>>(invcov, mean, s_ws, out);
}